// Round 17
// baseline (168.740 us; speedup 1.0000x reference)
//
#include <hip/hip_runtime.h>

#define NN 50000
#define NE 800000
#define C 64
#define NL 4
#define NBK 196            // buckets = ceil(50000/256)
#define HBLK 782           // ceil(NE/1024)

typedef __attribute__((ext_vector_type(8))) short bf16x8;
typedef __attribute__((ext_vector_type(4))) float f32x4;

// ---- bf16 helpers (RNE) ----
__device__ __forceinline__ unsigned short f2bf(float f) {
    unsigned u = __float_as_uint(f);
    u += 0x7fffu + ((u >> 16) & 1u);
    return (unsigned short)(u >> 16);
}

// ---------------- K1: per-block LDS bucket histogram + local rank ----------------
__global__ __launch_bounds__(1024) void bucket_hist_kernel(const int* __restrict__ dst,
                                                           int* __restrict__ blk_cnt,
                                                           int* __restrict__ lrank) {
    __shared__ int cnt[NBK];
    int tid = threadIdx.x;
    int blk = blockIdx.x;
    if (tid < NBK) cnt[tid] = 0;
    __syncthreads();
    int e = blk * 1024 + tid;
    if (e < NE) lrank[e] = atomicAdd(&cnt[dst[e] >> 8], 1);
    __syncthreads();
    if (tid < NBK) blk_cnt[tid * HBLK + blk] = cnt[tid];   // layout [bucket][blk]
}

// ---------------- K2: per-bucket exclusive scan over its 782 block counts ----------------
__global__ __launch_bounds__(1024) void scanblk_kernel(int* __restrict__ blk_cnt,
                                                       int* __restrict__ bucket_tot) {
    __shared__ int sdata[1024];
    int b = blockIdx.x;
    int tid = threadIdx.x;
    int v = (tid < HBLK) ? blk_cnt[b * HBLK + tid] : 0;
    sdata[tid] = v;
    __syncthreads();
    for (int off = 1; off < 1024; off <<= 1) {
        int t = (tid >= off) ? sdata[tid - off] : 0;
        __syncthreads();
        sdata[tid] += t;
        __syncthreads();
    }
    if (tid < HBLK) blk_cnt[b * HBLK + tid] = sdata[tid] - v;   // exclusive, in place
    if (tid == HBLK - 1) bucket_tot[b] = sdata[tid];
}

// ---------------- K3: scatter edges, PACKED (src<<8 | local_dst) ----------------
__global__ __launch_bounds__(1024) void bucket_scatter_kernel(
    const int* __restrict__ src, const int* __restrict__ dst,
    const int* __restrict__ lrank, const int* __restrict__ base2,
    const int* __restrict__ bucket_tot, int* __restrict__ sorted) {
    __shared__ int sscan[256];
    __shared__ int sex[256];
    int tid = threadIdx.x;
    int blk = blockIdx.x;
    int v0 = 0;
    if (tid < 256) {
        v0 = (tid < NBK) ? bucket_tot[tid] : 0;
        sscan[tid] = v0;
    }
    __syncthreads();
    for (int off = 1; off < 256; off <<= 1) {
        int t = (tid < 256 && tid >= off) ? sscan[tid - off] : 0;
        __syncthreads();
        if (tid < 256) sscan[tid] += t;
        __syncthreads();
    }
    if (tid < 256) sex[tid] = sscan[tid] - v0;
    __syncthreads();

    int e = blk * 1024 + tid;
    if (e < NE) {
        int d = dst[e];
        int b = d >> 8;
        int pos = sex[b] + base2[b * HBLK + blk] + lrank[e];
        sorted[pos] = (src[e] << 8) | (d & 255);
    }
}

// ---------------- K4: per-bucket finalize: deg + scan + row_start/deg_inv + CSR fill ----------------
__global__ __launch_bounds__(512) void bucket_finalize_kernel(
    const int* __restrict__ sorted, const int* __restrict__ bucket_tot,
    int* __restrict__ row_start, int* __restrict__ deg, float* __restrict__ deg_inv,
    int* __restrict__ csr_src) {
    __shared__ int sscan[256];
    __shared__ int ldeg[256];
    __shared__ int lpre[256];
    __shared__ int lcnt[256];

    int b = blockIdx.x;
    int tid = threadIdx.x;
    int v0 = 0;
    if (tid < 256) {
        v0 = (tid < NBK) ? bucket_tot[tid] : 0;
        sscan[tid] = v0;
        ldeg[tid] = 0;
        lcnt[tid] = 0;
    }
    __syncthreads();
    for (int off = 1; off < 256; off <<= 1) {
        int t = (tid < 256 && tid >= off) ? sscan[tid - off] : 0;
        __syncthreads();
        if (tid < 256) sscan[tid] += t;
        __syncthreads();
    }
    int lo = (b == 0) ? 0 : sscan[b - 1];
    int hi = sscan[b];
    __syncthreads();

    for (int i = lo + tid; i < hi; i += 512)
        atomicAdd(&ldeg[sorted[i] & 255], 1);
    __syncthreads();

    int dv = 0;
    if (tid < 256) {
        dv = ldeg[tid];
        lpre[tid] = dv;
    }
    __syncthreads();
    for (int off = 1; off < 256; off <<= 1) {
        int t = (tid < 256 && tid >= off) ? lpre[tid - off] : 0;
        __syncthreads();
        if (tid < 256) lpre[tid] += t;
        __syncthreads();
    }
    if (tid < 256) {
        int p = lpre[tid] - dv;
        lpre[tid] = p;
        int n = b * 256 + tid;
        if (n < NN) {
            row_start[n] = lo + p;
            deg[n] = dv;
            deg_inv[n] = 1.0f / fmaxf((float)dv, 1.0f);
        }
    }
    __syncthreads();

    for (int i = lo + tid; i < hi; i += 512) {
        int p = sorted[i];
        int loc = p & 255;
        int r = atomicAdd(&lcnt[loc], 1);
        csr_src[lo + lpre[loc] + r] = (int)((unsigned)p >> 8);
    }
}

// ---------------- layer-0 transform via MFMA (validated R13) ----------------
__global__ __launch_bounds__(512) void transform_mfma_kernel(
    const float* __restrict__ xin,
    const float* __restrict__ Wl, const float* __restrict__ Wr,
    const float* __restrict__ bias,
    unsigned short* __restrict__ y, float* __restrict__ z)
{
    __shared__ unsigned short xs[64][72];
    __shared__ unsigned short wlT[64][72];
    __shared__ unsigned short wrT[64][72];
    __shared__ unsigned short ys[64][64];
    __shared__ float zs[64][64];
    __shared__ float bs[C];

    int tid = threadIdx.x;
    int node0 = blockIdx.x * 64;

    for (int i = tid; i < C * C; i += 512) {
        int k = i >> 6, c = i & 63;
        wlT[c][k] = f2bf(Wl[i]);
        wrT[c][k] = f2bf(Wr[i]);
    }
    if (tid < C) bs[tid] = bias[tid];
    for (int i = tid; i < 64 * 16; i += 512) {
        int nl = i >> 4, c4 = i & 15;
        int n = node0 + nl;
        int nc = n < NN ? n : NN - 1;
        float4 v = ((const float4*)xin)[(size_t)nc * 16 + c4];
        xs[nl][c4 * 4 + 0] = f2bf(v.x);
        xs[nl][c4 * 4 + 1] = f2bf(v.y);
        xs[nl][c4 * 4 + 2] = f2bf(v.z);
        xs[nl][c4 * 4 + 3] = f2bf(v.w);
    }
    __syncthreads();

    int w = tid >> 6;
    int l = tid & 63;
    int mt = w >> 1;
    int half = w & 1;
    int r16 = l & 15;
    int kg = l >> 4;

    bf16x8 a0 = *(const bf16x8*)&xs[mt * 16 + r16][kg * 8];
    bf16x8 a1 = *(const bf16x8*)&xs[mt * 16 + r16][32 + kg * 8];

    f32x4 acc[4];
    #pragma unroll
    for (int nt = 0; nt < 4; nt++) {
        float bv = half ? bs[nt * 16 + r16] : 0.f;
        acc[nt] = (f32x4){bv, bv, bv, bv};
    }
    #pragma unroll
    for (int nt = 0; nt < 4; nt++) {
        const unsigned short* col = half ? &wrT[nt * 16 + r16][0] : &wlT[nt * 16 + r16][0];
        bf16x8 b0 = *(const bf16x8*)&col[kg * 8];
        bf16x8 b1 = *(const bf16x8*)&col[32 + kg * 8];
        acc[nt] = __builtin_amdgcn_mfma_f32_16x16x32_bf16(a0, b0, acc[nt], 0, 0, 0);
        acc[nt] = __builtin_amdgcn_mfma_f32_16x16x32_bf16(a1, b1, acc[nt], 0, 0, 0);
    }
    #pragma unroll
    for (int nt = 0; nt < 4; nt++) {
        #pragma unroll
        for (int j = 0; j < 4; j++) {
            int r = mt * 16 + kg * 4 + j;
            int c = nt * 16 + r16;
            if (half) zs[r][c] = acc[nt][j];
            else      ys[r][c] = f2bf(acc[nt][j]);
        }
    }
    __syncthreads();

    for (int i = tid; i < 64 * 16; i += 512) {
        int r = i >> 4, g = i & 15;
        int n = node0 + r;
        if (n < NN) {
            ((ushort4*)&y[(size_t)n * C])[g] = ((const ushort4*)&ys[r][0])[g];
            ((float4*)&z[(size_t)n * C])[g] = ((const float4*)&zs[r][0])[g];
        }
    }
}

// ---------------- gather core: 8 lanes/node, uint4 (16B) loads, masked unroll-8 ----------------
// row = 64 bf16 = 128B = 8 uint4; lane ql owns channels ql*8..ql*8+7
__device__ __forceinline__ void gather_row8(const uint4* __restrict__ yb4,
                                            const int* __restrict__ cp, int d, int ql,
                                            float* __restrict__ acc) {
    for (int t = 0; t < d; t += 8) {
        int lim = d - 1 - t;
        int j1 = min(1, lim), j2 = min(2, lim), j3 = min(3, lim);
        int j4 = min(4, lim), j5 = min(5, lim), j6 = min(6, lim), j7 = min(7, lim);
        float m1 = lim >= 1 ? 1.f : 0.f, m2 = lim >= 2 ? 1.f : 0.f;
        float m3 = lim >= 3 ? 1.f : 0.f, m4 = lim >= 4 ? 1.f : 0.f;
        float m5 = lim >= 5 ? 1.f : 0.f, m6 = lim >= 6 ? 1.f : 0.f;
        float m7 = lim >= 7 ? 1.f : 0.f;
        int s0 = cp[t];
        int s1 = cp[t + j1];
        int s2 = cp[t + j2];
        int s3 = cp[t + j3];
        int s4 = cp[t + j4];
        int s5 = cp[t + j5];
        int s6 = cp[t + j6];
        int s7 = cp[t + j7];
        uint4 p0 = yb4[(size_t)s0 * 8 + ql];
        uint4 p1 = yb4[(size_t)s1 * 8 + ql];
        uint4 p2 = yb4[(size_t)s2 * 8 + ql];
        uint4 p3 = yb4[(size_t)s3 * 8 + ql];
        uint4 p4 = yb4[(size_t)s4 * 8 + ql];
        uint4 p5 = yb4[(size_t)s5 * 8 + ql];
        uint4 p6 = yb4[(size_t)s6 * 8 + ql];
        uint4 p7 = yb4[(size_t)s7 * 8 + ql];
        #define ACC8(P, M) \
            acc[0] += (M) * __uint_as_float((P).x << 16); \
            acc[1] += (M) * __uint_as_float((P).x & 0xffff0000u); \
            acc[2] += (M) * __uint_as_float((P).y << 16); \
            acc[3] += (M) * __uint_as_float((P).y & 0xffff0000u); \
            acc[4] += (M) * __uint_as_float((P).z << 16); \
            acc[5] += (M) * __uint_as_float((P).z & 0xffff0000u); \
            acc[6] += (M) * __uint_as_float((P).w << 16); \
            acc[7] += (M) * __uint_as_float((P).w & 0xffff0000u);
        ACC8(p0, 1.f) ACC8(p1, m1) ACC8(p2, m2) ACC8(p3, m3)
        ACC8(p4, m4) ACC8(p5, m5) ACC8(p6, m6) ACC8(p7, m7)
        #undef ACC8
    }
}

// ---------------- fused: gather 64 nodes (8 lanes each) -> prelu -> bf16 LDS -> M=64 MFMA ----------------
__global__ __launch_bounds__(512) void fused_gt_kernel(
    const uint4* __restrict__ yb4, const float4* __restrict__ z4,
    const int* __restrict__ row_start, const int* __restrict__ deg,
    const float* __restrict__ deg_inv, const float* __restrict__ alpha,
    const int* __restrict__ csr_src,
    const float* __restrict__ Wl2, const float* __restrict__ Wr2,
    const float* __restrict__ bias2,
    unsigned short* __restrict__ yout, float* __restrict__ zout)
{
    __shared__ unsigned short wlT[64][72];
    __shared__ unsigned short wrT[64][72];
    __shared__ unsigned short xsb[64][72];
    __shared__ unsigned short ys[64][64];
    __shared__ float zs[64][64];
    __shared__ float bs2[C];

    int tid = threadIdx.x;
    for (int i = tid; i < C * C; i += 512) {
        int k = i >> 6, c = i & 63;
        wlT[c][k] = f2bf(Wl2[i]);
        wrT[c][k] = f2bf(Wr2[i]);
    }
    if (tid < C) bs2[tid] = bias2[tid];

    int nl = tid >> 3;        // 0..63
    int ql = tid & 7;         // 0..7
    int n = blockIdx.x * 64 + nl;

    float acc[8] = {0.f, 0.f, 0.f, 0.f, 0.f, 0.f, 0.f, 0.f};
    float o[8] = {0.f, 0.f, 0.f, 0.f, 0.f, 0.f, 0.f, 0.f};
    if (n < NN) {
        int rs = row_start[n];
        int d = deg[n];
        gather_row8(yb4, csr_src + rs, d, ql, acc);
        float di = deg_inv[n];
        float4 zlo = z4[(size_t)n * 16 + ql * 2];
        float4 zhi = z4[(size_t)n * 16 + ql * 2 + 1];
        float4 alo = ((const float4*)alpha)[ql * 2];
        float4 ahi = ((const float4*)alpha)[ql * 2 + 1];
        float zv[8] = {zlo.x, zlo.y, zlo.z, zlo.w, zhi.x, zhi.y, zhi.z, zhi.w};
        float av[8] = {alo.x, alo.y, alo.z, alo.w, ahi.x, ahi.y, ahi.z, ahi.w};
        #pragma unroll
        for (int j = 0; j < 8; j++) {
            float t = di * acc[j] + zv[j];
            o[j] = t >= 0.f ? t : av[j] * t;
        }
    }
    {
        ushort4 lo = make_ushort4(f2bf(o[0]), f2bf(o[1]), f2bf(o[2]), f2bf(o[3]));
        ushort4 hi = make_ushort4(f2bf(o[4]), f2bf(o[5]), f2bf(o[6]), f2bf(o[7]));
        *(ushort4*)&xsb[nl][ql * 8] = lo;
        *(ushort4*)&xsb[nl][ql * 8 + 4] = hi;
    }
    __syncthreads();

    // M=64 MFMA transform (same mapping as transform_mfma, validated)
    int w = tid >> 6;
    int l = tid & 63;
    int mt = w >> 1;
    int half = w & 1;
    int r16 = l & 15;
    int kg = l >> 4;

    bf16x8 a0 = *(const bf16x8*)&xsb[mt * 16 + r16][kg * 8];
    bf16x8 a1 = *(const bf16x8*)&xsb[mt * 16 + r16][32 + kg * 8];

    #pragma unroll
    for (int nt = 0; nt < 4; nt++) {
        const unsigned short* col = half ? &wrT[nt * 16 + r16][0] : &wlT[nt * 16 + r16][0];
        bf16x8 b0 = *(const bf16x8*)&col[kg * 8];
        bf16x8 b1 = *(const bf16x8*)&col[32 + kg * 8];
        float bv = half ? bs2[nt * 16 + r16] : 0.f;
        f32x4 a4 = (f32x4){bv, bv, bv, bv};
        a4 = __builtin_amdgcn_mfma_f32_16x16x32_bf16(a0, b0, a4, 0, 0, 0);
        a4 = __builtin_amdgcn_mfma_f32_16x16x32_bf16(a1, b1, a4, 0, 0, 0);
        #pragma unroll
        for (int j = 0; j < 4; j++) {
            int r = mt * 16 + kg * 4 + j;
            int c = nt * 16 + r16;
            if (half) zs[r][c] = a4[j];
            else      ys[r][c] = f2bf(a4[j]);
        }
    }
    __syncthreads();

    for (int i = tid; i < 64 * 16; i += 512) {
        int r = i >> 4, g = i & 15;
        int n2 = blockIdx.x * 64 + r;
        if (n2 < NN) {
            ((ushort4*)&yout[(size_t)n2 * C])[g] = ((const ushort4*)&ys[r][0])[g];
            ((float4*)&zout[(size_t)n2 * C])[g] = ((const float4*)&zs[r][0])[g];
        }
    }
}

// ---------------- final gather (layer 3): 8 lanes/node, writes d_out fp32 ----------------
__global__ __launch_bounds__(256) void gather_kernel(
    const uint4* __restrict__ yb4, const float4* __restrict__ z4,
    const int* __restrict__ row_start, const int* __restrict__ deg,
    const float* __restrict__ deg_inv, const float* __restrict__ alpha,
    const int* __restrict__ csr_src,
    float4* __restrict__ out4)
{
    int tid = threadIdx.x;
    int n = blockIdx.x * 32 + (tid >> 3);
    int ql = tid & 7;
    if (n >= NN) return;

    int rs = row_start[n];
    int d = deg[n];
    float acc[8] = {0.f, 0.f, 0.f, 0.f, 0.f, 0.f, 0.f, 0.f};
    gather_row8(yb4, csr_src + rs, d, ql, acc);

    float di = deg_inv[n];
    float4 zlo = z4[(size_t)n * 16 + ql * 2];
    float4 zhi = z4[(size_t)n * 16 + ql * 2 + 1];
    float4 alo = ((const float4*)alpha)[ql * 2];
    float4 ahi = ((const float4*)alpha)[ql * 2 + 1];
    float zv[8] = {zlo.x, zlo.y, zlo.z, zlo.w, zhi.x, zhi.y, zhi.z, zhi.w};
    float av[8] = {alo.x, alo.y, alo.z, alo.w, ahi.x, ahi.y, ahi.z, ahi.w};
    float o[8];
    #pragma unroll
    for (int j = 0; j < 8; j++) {
        float t = di * acc[j] + zv[j];
        o[j] = t >= 0.f ? t : av[j] * t;
    }
    out4[(size_t)n * 16 + ql * 2]     = make_float4(o[0], o[1], o[2], o[3]);
    out4[(size_t)n * 16 + ql * 2 + 1] = make_float4(o[4], o[5], o[6], o[7]);
}

extern "C" void kernel_launch(void* const* d_in, const int* in_sizes, int n_in,
                              void* d_out, int out_size, void* d_ws, size_t ws_size,
                              hipStream_t stream) {
    const float* x     = (const float*)d_in[0];
    const int*   ei    = (const int*)d_in[1];
    const float* Wl    = (const float*)d_in[2];
    const float* Wr    = (const float*)d_in[3];
    const float* b     = (const float*)d_in[4];
    const float* alpha = (const float*)d_in[5];
    float* out = (float*)d_out;

    const int* src = ei;        // edge_index[0]
    const int* dst = ei + NE;   // edge_index[1]

    // workspace layout
    char* wsp = (char*)d_ws;
    int*  lrank        = (int*)wsp;                 wsp += (size_t)NE * 4;   // aliased by csr_src
    int*  blk_cnt      = (int*)wsp;                 wsp += (size_t)NBK * HBLK * 4 + 256;
    int*  bucket_tot   = (int*)wsp;                 wsp += 1024;
    int*  sorted       = (int*)wsp;                 wsp += (size_t)NE * 4;   // packed (src<<8|ldst)
    int*  deg          = (int*)wsp;                 wsp += (size_t)(NBK * 256) * 4;
    float* deg_inv     = (float*)wsp;               wsp += (size_t)NN * 4;
    int*  row_start    = (int*)wsp;                 wsp += (size_t)NN * 4;
    unsigned short* y0buf = (unsigned short*)wsp;   wsp += (size_t)NN * C * 2;
    unsigned short* y1buf = (unsigned short*)wsp;   wsp += (size_t)NN * C * 2;
    float* z0buf       = (float*)wsp;               wsp += (size_t)NN * C * 4;
    float* z1buf       = (float*)wsp;
    int*  csr_src      = lrank;   // lrank dead after bucket_scatter

    // ---- CSR build: bucket-sorted, LDS-atomic only, 4 kernels ----
    bucket_hist_kernel<<<HBLK, 1024, 0, stream>>>(dst, blk_cnt, lrank);
    scanblk_kernel<<<NBK, 1024, 0, stream>>>(blk_cnt, bucket_tot);
    bucket_scatter_kernel<<<HBLK, 1024, 0, stream>>>(src, dst, lrank, blk_cnt,
                                                     bucket_tot, sorted);
    bucket_finalize_kernel<<<NBK, 512, 0, stream>>>(sorted, bucket_tot,
                                                    row_start, deg, deg_inv, csr_src);

    // ---- layer-0 transform (MFMA) ----
    transform_mfma_kernel<<<(NN + 63) / 64, 512, 0, stream>>>(x, Wl, Wr, b, y0buf, z0buf);

    // ---- fused (gather_l + MFMA transform_{l+1}) for l = 0,1,2; ping-pong ----
    const int fblocks = (NN + 63) / 64;   // 782
    unsigned short* ycur = y0buf; float* zcur = z0buf;
    unsigned short* ynxt = y1buf; float* znxt = z1buf;
    for (int l = 0; l < NL - 1; l++) {
        fused_gt_kernel<<<fblocks, 512, 0, stream>>>(
            (const uint4*)ycur, (const float4*)zcur,
            row_start, deg, deg_inv, alpha + (size_t)l * C, csr_src,
            Wl + (size_t)(l + 1) * C * C, Wr + (size_t)(l + 1) * C * C,
            b + (size_t)(l + 1) * C,
            ynxt, znxt);
        unsigned short* ty = ycur; float* tz = zcur;
        ycur = ynxt; zcur = znxt;
        ynxt = ty;   znxt = tz;
    }

    // ---- final gather (layer 3) -> d_out ----
    gather_kernel<<<(NN + 31) / 32, 256, 0, stream>>>(
        (const uint4*)ycur, (const float4*)zcur, row_start, deg,
        deg_inv, alpha + (size_t)(NL - 1) * C, csr_src, (float4*)out);
}

// Round 18
// 158.339 us; speedup vs baseline: 1.0657x; 1.0657x over previous
//
#include <hip/hip_runtime.h>

#define NN 50000
#define NE 800000
#define C 64
#define NL 4
#define NBK 196            // buckets = ceil(50000/256)
#define HBLK 782           // ceil(NE/1024)

typedef __attribute__((ext_vector_type(8))) short bf16x8;
typedef __attribute__((ext_vector_type(4))) float f32x4;

// ---- bf16 helpers (RNE) ----
__device__ __forceinline__ unsigned short f2bf(float f) {
    unsigned u = __float_as_uint(f);
    u += 0x7fffu + ((u >> 16) & 1u);
    return (unsigned short)(u >> 16);
}
__device__ __forceinline__ float4 bf4_to_f4(uint2 p) {
    float4 r;
    r.x = __uint_as_float(p.x << 16);
    r.y = __uint_as_float(p.x & 0xffff0000u);
    r.z = __uint_as_float(p.y << 16);
    r.w = __uint_as_float(p.y & 0xffff0000u);
    return r;
}

// ---------------- K1: per-block LDS bucket histogram + local rank ----------------
__global__ __launch_bounds__(1024) void bucket_hist_kernel(const int* __restrict__ dst,
                                                           int* __restrict__ blk_cnt,
                                                           int* __restrict__ lrank) {
    __shared__ int cnt[NBK];
    int tid = threadIdx.x;
    int blk = blockIdx.x;
    if (tid < NBK) cnt[tid] = 0;
    __syncthreads();
    int e = blk * 1024 + tid;
    if (e < NE) lrank[e] = atomicAdd(&cnt[dst[e] >> 8], 1);
    __syncthreads();
    if (tid < NBK) blk_cnt[tid * HBLK + blk] = cnt[tid];   // layout [bucket][blk]
}

// ---------------- K2: per-bucket exclusive scan over its 782 block counts ----------------
__global__ __launch_bounds__(1024) void scanblk_kernel(int* __restrict__ blk_cnt,
                                                       int* __restrict__ bucket_tot) {
    __shared__ int sdata[1024];
    int b = blockIdx.x;
    int tid = threadIdx.x;
    int v = (tid < HBLK) ? blk_cnt[b * HBLK + tid] : 0;
    sdata[tid] = v;
    __syncthreads();
    for (int off = 1; off < 1024; off <<= 1) {
        int t = (tid >= off) ? sdata[tid - off] : 0;
        __syncthreads();
        sdata[tid] += t;
        __syncthreads();
    }
    if (tid < HBLK) blk_cnt[b * HBLK + tid] = sdata[tid] - v;   // exclusive, in place
    if (tid == HBLK - 1) bucket_tot[b] = sdata[tid];
}

// ---------------- K3: scatter edges, PACKED (src<<8 | local_dst) ----------------
__global__ __launch_bounds__(1024) void bucket_scatter_kernel(
    const int* __restrict__ src, const int* __restrict__ dst,
    const int* __restrict__ lrank, const int* __restrict__ base2,
    const int* __restrict__ bucket_tot, int* __restrict__ sorted) {
    __shared__ int sscan[256];
    __shared__ int sex[256];
    int tid = threadIdx.x;
    int blk = blockIdx.x;
    int v0 = 0;
    if (tid < 256) {
        v0 = (tid < NBK) ? bucket_tot[tid] : 0;
        sscan[tid] = v0;
    }
    __syncthreads();
    for (int off = 1; off < 256; off <<= 1) {
        int t = (tid < 256 && tid >= off) ? sscan[tid - off] : 0;
        __syncthreads();
        if (tid < 256) sscan[tid] += t;
        __syncthreads();
    }
    if (tid < 256) sex[tid] = sscan[tid] - v0;
    __syncthreads();

    int e = blk * 1024 + tid;
    if (e < NE) {
        int d = dst[e];
        int b = d >> 8;
        int pos = sex[b] + base2[b * HBLK + blk] + lrank[e];
        sorted[pos] = (src[e] << 8) | (d & 255);
    }
}

// ---------------- K4: per-bucket finalize: deg + scan + row_start/deg_inv + CSR fill ----------------
__global__ __launch_bounds__(512) void bucket_finalize_kernel(
    const int* __restrict__ sorted, const int* __restrict__ bucket_tot,
    int* __restrict__ row_start, int* __restrict__ deg, float* __restrict__ deg_inv,
    int* __restrict__ csr_src) {
    __shared__ int sscan[256];
    __shared__ int ldeg[256];
    __shared__ int lpre[256];
    __shared__ int lcnt[256];

    int b = blockIdx.x;
    int tid = threadIdx.x;
    int v0 = 0;
    if (tid < 256) {
        v0 = (tid < NBK) ? bucket_tot[tid] : 0;
        sscan[tid] = v0;
        ldeg[tid] = 0;
        lcnt[tid] = 0;
    }
    __syncthreads();
    for (int off = 1; off < 256; off <<= 1) {
        int t = (tid < 256 && tid >= off) ? sscan[tid - off] : 0;
        __syncthreads();
        if (tid < 256) sscan[tid] += t;
        __syncthreads();
    }
    int lo = (b == 0) ? 0 : sscan[b - 1];
    int hi = sscan[b];
    __syncthreads();

    for (int i = lo + tid; i < hi; i += 512)
        atomicAdd(&ldeg[sorted[i] & 255], 1);
    __syncthreads();

    int dv = 0;
    if (tid < 256) {
        dv = ldeg[tid];
        lpre[tid] = dv;
    }
    __syncthreads();
    for (int off = 1; off < 256; off <<= 1) {
        int t = (tid < 256 && tid >= off) ? lpre[tid - off] : 0;
        __syncthreads();
        if (tid < 256) lpre[tid] += t;
        __syncthreads();
    }
    if (tid < 256) {
        int p = lpre[tid] - dv;
        lpre[tid] = p;
        int n = b * 256 + tid;
        if (n < NN) {
            row_start[n] = lo + p;
            deg[n] = dv;
            deg_inv[n] = 1.0f / fmaxf((float)dv, 1.0f);
        }
    }
    __syncthreads();

    for (int i = lo + tid; i < hi; i += 512) {
        int p = sorted[i];
        int loc = p & 255;
        int r = atomicAdd(&lcnt[loc], 1);
        csr_src[lo + lpre[loc] + r] = (int)((unsigned)p >> 8);
    }
}

// ---------------- layer-0 transform via MFMA (validated R13) ----------------
__global__ __launch_bounds__(512) void transform_mfma_kernel(
    const float* __restrict__ xin,
    const float* __restrict__ Wl, const float* __restrict__ Wr,
    const float* __restrict__ bias,
    unsigned short* __restrict__ y, float* __restrict__ z)
{
    __shared__ unsigned short xs[64][72];
    __shared__ unsigned short wlT[64][72];
    __shared__ unsigned short wrT[64][72];
    __shared__ unsigned short ys[64][64];
    __shared__ float zs[64][64];
    __shared__ float bs[C];

    int tid = threadIdx.x;
    int node0 = blockIdx.x * 64;

    for (int i = tid; i < C * C; i += 512) {
        int k = i >> 6, c = i & 63;
        wlT[c][k] = f2bf(Wl[i]);
        wrT[c][k] = f2bf(Wr[i]);
    }
    if (tid < C) bs[tid] = bias[tid];
    for (int i = tid; i < 64 * 16; i += 512) {
        int nl = i >> 4, c4 = i & 15;
        int n = node0 + nl;
        int nc = n < NN ? n : NN - 1;
        float4 v = ((const float4*)xin)[(size_t)nc * 16 + c4];
        xs[nl][c4 * 4 + 0] = f2bf(v.x);
        xs[nl][c4 * 4 + 1] = f2bf(v.y);
        xs[nl][c4 * 4 + 2] = f2bf(v.z);
        xs[nl][c4 * 4 + 3] = f2bf(v.w);
    }
    __syncthreads();

    int w = tid >> 6;
    int l = tid & 63;
    int mt = w >> 1;
    int half = w & 1;
    int r16 = l & 15;
    int kg = l >> 4;

    bf16x8 a0 = *(const bf16x8*)&xs[mt * 16 + r16][kg * 8];
    bf16x8 a1 = *(const bf16x8*)&xs[mt * 16 + r16][32 + kg * 8];

    f32x4 acc[4];
    #pragma unroll
    for (int nt = 0; nt < 4; nt++) {
        float bv = half ? bs[nt * 16 + r16] : 0.f;
        acc[nt] = (f32x4){bv, bv, bv, bv};
    }
    #pragma unroll
    for (int nt = 0; nt < 4; nt++) {
        const unsigned short* col = half ? &wrT[nt * 16 + r16][0] : &wlT[nt * 16 + r16][0];
        bf16x8 b0 = *(const bf16x8*)&col[kg * 8];
        bf16x8 b1 = *(const bf16x8*)&col[32 + kg * 8];
        acc[nt] = __builtin_amdgcn_mfma_f32_16x16x32_bf16(a0, b0, acc[nt], 0, 0, 0);
        acc[nt] = __builtin_amdgcn_mfma_f32_16x16x32_bf16(a1, b1, acc[nt], 0, 0, 0);
    }
    #pragma unroll
    for (int nt = 0; nt < 4; nt++) {
        #pragma unroll
        for (int j = 0; j < 4; j++) {
            int r = mt * 16 + kg * 4 + j;
            int c = nt * 16 + r16;
            if (half) zs[r][c] = acc[nt][j];
            else      ys[r][c] = f2bf(acc[nt][j]);
        }
    }
    __syncthreads();

    for (int i = tid; i < 64 * 16; i += 512) {
        int r = i >> 4, g = i & 15;
        int n = node0 + r;
        if (n < NN) {
            ((ushort4*)&y[(size_t)n * C])[g] = ((const ushort4*)&ys[r][0])[g];
            ((float4*)&z[(size_t)n * C])[g] = ((const float4*)&zs[r][0])[g];
        }
    }
}

// ---------------- gather core: bf16 rows, 16 lanes/node, uint2, masked unroll-8 ----------------
__device__ __forceinline__ float4 gather_row(const uint2* __restrict__ yb,
                                             const int* __restrict__ cp, int d, int ql) {
    float4 acc = make_float4(0.f, 0.f, 0.f, 0.f);
    for (int t = 0; t < d; t += 8) {
        int lim = d - 1 - t;
        int j1 = min(1, lim), j2 = min(2, lim), j3 = min(3, lim);
        int j4 = min(4, lim), j5 = min(5, lim), j6 = min(6, lim), j7 = min(7, lim);
        float m1 = lim >= 1 ? 1.f : 0.f, m2 = lim >= 2 ? 1.f : 0.f;
        float m3 = lim >= 3 ? 1.f : 0.f, m4 = lim >= 4 ? 1.f : 0.f;
        float m5 = lim >= 5 ? 1.f : 0.f, m6 = lim >= 6 ? 1.f : 0.f;
        float m7 = lim >= 7 ? 1.f : 0.f;
        int s0 = cp[t];
        int s1 = cp[t + j1];
        int s2 = cp[t + j2];
        int s3 = cp[t + j3];
        int s4 = cp[t + j4];
        int s5 = cp[t + j5];
        int s6 = cp[t + j6];
        int s7 = cp[t + j7];
        uint2 p0 = yb[(size_t)s0 * 16 + ql];
        uint2 p1 = yb[(size_t)s1 * 16 + ql];
        uint2 p2 = yb[(size_t)s2 * 16 + ql];
        uint2 p3 = yb[(size_t)s3 * 16 + ql];
        uint2 p4 = yb[(size_t)s4 * 16 + ql];
        uint2 p5 = yb[(size_t)s5 * 16 + ql];
        uint2 p6 = yb[(size_t)s6 * 16 + ql];
        uint2 p7 = yb[(size_t)s7 * 16 + ql];
        float4 v0 = bf4_to_f4(p0);
        float4 v1 = bf4_to_f4(p1);
        float4 v2 = bf4_to_f4(p2);
        float4 v3 = bf4_to_f4(p3);
        float4 v4 = bf4_to_f4(p4);
        float4 v5 = bf4_to_f4(p5);
        float4 v6 = bf4_to_f4(p6);
        float4 v7 = bf4_to_f4(p7);
        acc.x += v0.x;      acc.y += v0.y;      acc.z += v0.z;      acc.w += v0.w;
        acc.x += v1.x * m1; acc.y += v1.y * m1; acc.z += v1.z * m1; acc.w += v1.w * m1;
        acc.x += v2.x * m2; acc.y += v2.y * m2; acc.z += v2.z * m2; acc.w += v2.w * m2;
        acc.x += v3.x * m3; acc.y += v3.y * m3; acc.z += v3.z * m3; acc.w += v3.w * m3;
        acc.x += v4.x * m4; acc.y += v4.y * m4; acc.z += v4.z * m4; acc.w += v4.w * m4;
        acc.x += v5.x * m5; acc.y += v5.y * m5; acc.z += v5.z * m5; acc.w += v5.w * m5;
        acc.x += v6.x * m6; acc.y += v6.y * m6; acc.z += v6.z * m6; acc.w += v6.w * m6;
        acc.x += v7.x * m7; acc.y += v7.y * m7; acc.z += v7.z * m7; acc.w += v7.w * m7;
    }
    return acc;
}

// ---------------- fused: gather layer l -> prelu -> bf16 LDS -> MFMA transform l+1 ----------------
// 512 threads = 8 waves; gather: 32 nodes x 16 lanes; transform: M=32,N=64,K=64 MFMA.
__global__ __launch_bounds__(512) void fused_gt_kernel(
    const uint2* __restrict__ yb, const float4* __restrict__ z4,
    const int* __restrict__ row_start, const int* __restrict__ deg,
    const float* __restrict__ deg_inv, const float* __restrict__ alpha,
    const int* __restrict__ csr_src,
    const float* __restrict__ Wl2, const float* __restrict__ Wr2,
    const float* __restrict__ bias2,
    unsigned short* __restrict__ yout, float* __restrict__ zout)
{
    __shared__ unsigned short wlT[64][72];
    __shared__ unsigned short wrT[64][72];
    __shared__ unsigned short xsb[32][72];
    __shared__ unsigned short ys[32][64];
    __shared__ float zs[32][64];
    __shared__ float bs2[C];

    int tid = threadIdx.x;
    for (int i = tid; i < C * C; i += 512) {
        int k = i >> 6, c = i & 63;
        wlT[c][k] = f2bf(Wl2[i]);
        wrT[c][k] = f2bf(Wr2[i]);
    }
    if (tid < C) bs2[tid] = bias2[tid];

    int nl = tid >> 4;
    int ql = tid & 15;
    int n = blockIdx.x * 32 + nl;

    float4 o = make_float4(0.f, 0.f, 0.f, 0.f);
    if (n < NN) {
        int rs = row_start[n];
        int d = deg[n];
        float4 acc = gather_row(yb, csr_src + rs, d, ql);
        float di = deg_inv[n];
        float4 zz = z4[(size_t)n * 16 + ql];
        float4 a4 = ((const float4*)alpha)[ql];
        o.x = di * acc.x + zz.x;
        o.y = di * acc.y + zz.y;
        o.z = di * acc.z + zz.z;
        o.w = di * acc.w + zz.w;
        o.x = o.x >= 0.f ? o.x : a4.x * o.x;
        o.y = o.y >= 0.f ? o.y : a4.y * o.y;
        o.z = o.z >= 0.f ? o.z : a4.z * o.z;
        o.w = o.w >= 0.f ? o.w : a4.w * o.w;
    }
    {
        ushort4 p = make_ushort4(f2bf(o.x), f2bf(o.y), f2bf(o.z), f2bf(o.w));
        *(ushort4*)&xsb[nl][ql * 4] = p;
    }
    __syncthreads();

    int w = tid >> 6;
    int l = tid & 63;
    int mt = w & 1;
    int half = (w >> 1) & 1;
    int ntg = w >> 2;
    int r16 = l & 15;
    int kg = l >> 4;

    bf16x8 a0 = *(const bf16x8*)&xsb[mt * 16 + r16][kg * 8];
    bf16x8 a1 = *(const bf16x8*)&xsb[mt * 16 + r16][32 + kg * 8];

    #pragma unroll
    for (int q = 0; q < 2; q++) {
        int nt = ntg * 2 + q;
        const unsigned short* col = half ? &wrT[nt * 16 + r16][0] : &wlT[nt * 16 + r16][0];
        bf16x8 b0 = *(const bf16x8*)&col[kg * 8];
        bf16x8 b1 = *(const bf16x8*)&col[32 + kg * 8];
        float bv = half ? bs2[nt * 16 + r16] : 0.f;
        f32x4 acc = (f32x4){bv, bv, bv, bv};
        acc = __builtin_amdgcn_mfma_f32_16x16x32_bf16(a0, b0, acc, 0, 0, 0);
        acc = __builtin_amdgcn_mfma_f32_16x16x32_bf16(a1, b1, acc, 0, 0, 0);
        #pragma unroll
        for (int j = 0; j < 4; j++) {
            int r = mt * 16 + kg * 4 + j;
            int c = nt * 16 + r16;
            if (half) zs[r][c] = acc[j];
            else      ys[r][c] = f2bf(acc[j]);
        }
    }
    __syncthreads();

    {
        int r = tid >> 4, g = tid & 15;
        int n2 = blockIdx.x * 32 + r;
        if (n2 < NN) {
            ((ushort4*)&yout[(size_t)n2 * C])[g] = ((const ushort4*)&ys[r][0])[g];
            ((float4*)&zout[(size_t)n2 * C])[g] = ((const float4*)&zs[r][0])[g];
        }
    }
}

// ---------------- final gather (layer 3): writes d_out fp32 ----------------
__global__ __launch_bounds__(256) void gather_kernel(
    const uint2* __restrict__ yb, const float4* __restrict__ z4,
    const int* __restrict__ row_start, const int* __restrict__ deg,
    const float* __restrict__ deg_inv, const float* __restrict__ alpha,
    const int* __restrict__ csr_src,
    float4* __restrict__ out4)
{
    int tid = threadIdx.x;
    int n = blockIdx.x * 16 + (tid >> 4);
    int ql = tid & 15;

    int rs = row_start[n];
    int d = deg[n];
    float4 acc = gather_row(yb, csr_src + rs, d, ql);

    float di = deg_inv[n];
    float4 zz = z4[(size_t)n * 16 + ql];
    float4 a4 = ((const float4*)alpha)[ql];
    float4 o;
    o.x = di * acc.x + zz.x;
    o.y = di * acc.y + zz.y;
    o.z = di * acc.z + zz.z;
    o.w = di * acc.w + zz.w;
    o.x = o.x >= 0.f ? o.x : a4.x * o.x;
    o.y = o.y >= 0.f ? o.y : a4.y * o.y;
    o.z = o.z >= 0.f ? o.z : a4.z * o.z;
    o.w = o.w >= 0.f ? o.w : a4.w * o.w;
    out4[(size_t)n * 16 + ql] = o;
}

extern "C" void kernel_launch(void* const* d_in, const int* in_sizes, int n_in,
                              void* d_out, int out_size, void* d_ws, size_t ws_size,
                              hipStream_t stream) {
    const float* x     = (const float*)d_in[0];
    const int*   ei    = (const int*)d_in[1];
    const float* Wl    = (const float*)d_in[2];
    const float* Wr    = (const float*)d_in[3];
    const float* b     = (const float*)d_in[4];
    const float* alpha = (const float*)d_in[5];
    float* out = (float*)d_out;

    const int* src = ei;        // edge_index[0]
    const int* dst = ei + NE;   // edge_index[1]

    // workspace layout
    char* wsp = (char*)d_ws;
    int*  lrank        = (int*)wsp;                 wsp += (size_t)NE * 4;   // aliased by csr_src
    int*  blk_cnt      = (int*)wsp;                 wsp += (size_t)NBK * HBLK * 4 + 256;
    int*  bucket_tot   = (int*)wsp;                 wsp += 1024;
    int*  sorted       = (int*)wsp;                 wsp += (size_t)NE * 4;   // packed (src<<8|ldst)
    int*  deg          = (int*)wsp;                 wsp += (size_t)(NBK * 256) * 4;
    float* deg_inv     = (float*)wsp;               wsp += (size_t)NN * 4;
    int*  row_start    = (int*)wsp;                 wsp += (size_t)NN * 4;
    unsigned short* y0buf = (unsigned short*)wsp;   wsp += (size_t)NN * C * 2;
    unsigned short* y1buf = (unsigned short*)wsp;   wsp += (size_t)NN * C * 2;
    float* z0buf       = (float*)wsp;               wsp += (size_t)NN * C * 4;
    float* z1buf       = (float*)wsp;
    int*  csr_src      = lrank;   // lrank dead after bucket_scatter

    // ---- CSR build: bucket-sorted, LDS-atomic only, 4 kernels ----
    bucket_hist_kernel<<<HBLK, 1024, 0, stream>>>(dst, blk_cnt, lrank);
    scanblk_kernel<<<NBK, 1024, 0, stream>>>(blk_cnt, bucket_tot);
    bucket_scatter_kernel<<<HBLK, 1024, 0, stream>>>(src, dst, lrank, blk_cnt,
                                                     bucket_tot, sorted);
    bucket_finalize_kernel<<<NBK, 512, 0, stream>>>(sorted, bucket_tot,
                                                    row_start, deg, deg_inv, csr_src);

    // ---- layer-0 transform (MFMA) ----
    transform_mfma_kernel<<<(NN + 63) / 64, 512, 0, stream>>>(x, Wl, Wr, b, y0buf, z0buf);

    // ---- fused (gather_l + MFMA transform_{l+1}) for l = 0,1,2; ping-pong ----
    const int fblocks = (NN + 31) / 32;   // 1563
    unsigned short* ycur = y0buf; float* zcur = z0buf;
    unsigned short* ynxt = y1buf; float* znxt = z1buf;
    for (int l = 0; l < NL - 1; l++) {
        fused_gt_kernel<<<fblocks, 512, 0, stream>>>(
            (const uint2*)ycur, (const float4*)zcur,
            row_start, deg, deg_inv, alpha + (size_t)l * C, csr_src,
            Wl + (size_t)(l + 1) * C * C, Wr + (size_t)(l + 1) * C * C,
            b + (size_t)(l + 1) * C,
            ynxt, znxt);
        unsigned short* ty = ycur; float* tz = zcur;
        ycur = ynxt; zcur = znxt;
        ynxt = ty;   znxt = tz;
    }

    // ---- final gather (layer 3) -> d_out ----
    gather_kernel<<<NN / 16, 256, 0, stream>>>(
        (const uint2*)ycur, (const float4*)zcur, row_start, deg,
        deg_inv, alpha + (size_t)(NL - 1) * C, csr_src, (float4*)out);
}